// Round 4
// baseline (427.521 us; speedup 1.0000x reference)
//
#include <hip/hip_runtime.h>
#include <stdint.h>

#define TSEQ 2048
#define NB 2
#define EMB 1024
#define NHEAD 16
#define HDIM 64
#define KSPLIT 4
#define NT (TSEQ / KSPLIT / 64)   // 8 key-tiles per block
// 0.125 (D^-0.5) * log2(e), folded into Q at the in-proj epilogue
#define QSCALE 0.18033688f

typedef __bf16 bf16x8 __attribute__((ext_vector_type(8)));
typedef __bf16 bf16x4 __attribute__((ext_vector_type(4)));
typedef float f32x4 __attribute__((ext_vector_type(4)));
typedef float f32x16 __attribute__((ext_vector_type(16)));
typedef unsigned int u32x4 __attribute__((ext_vector_type(4)));

// async 16B global->LDS. lds base must be wave-uniform; HW scatters lane*16.
__device__ __forceinline__ void gload_lds16(const void* g, void* lds) {
    __builtin_amdgcn_global_load_lds(
        (const __attribute__((address_space(1))) unsigned int*)g,
        (__attribute__((address_space(3))) unsigned int*)lds, 16, 0, 0);
}

__device__ __forceinline__ float fast_exp2(float x) {
#if __has_builtin(__builtin_amdgcn_exp2f)
    return __builtin_amdgcn_exp2f(x);   // raw v_exp_f32; inputs bounded
#else
    return exp2f(x);
#endif
}

// packed f32 pair -> bf16x2 in one u32 (lo in [15:0], hi in [31:16])
__device__ __forceinline__ unsigned cvt_pk_bf16(float lo, float hi) {
    unsigned r;
    asm("v_cvt_pk_bf16_f32 %0, %1, %2" : "=v"(r) : "v"(lo), "v"(hi));
    return r;
}

// a[32:63] <-> b[0:31]
__device__ __forceinline__ void swap32(unsigned& a, unsigned& b) {
    asm("v_permlane32_swap_b32 %0, %1" : "+v"(a), "+v"(b));
}

__device__ __forceinline__ bf16x8 as_bf16x8(u32x4 u) {
    union { u32x4 u; bf16x8 h; } c;
    c.u = u;
    return c.h;
}

// ---------------------------------------------------------------------------
// merged prep: bid<4096 -> cvt x (4096x1024 f32 -> bf16);
// else transpose+cvt weights f32 [1024][sn] -> bf16 [sn][1024].
// grid 4096 + 128*32 = 8192, block 256.
// ---------------------------------------------------------------------------
__global__ __launch_bounds__(256) void prep_kernel(
    const float* __restrict__ x, const float* __restrict__ w_in,
    const float* __restrict__ w_out,
    __bf16* __restrict__ xb, __bf16* __restrict__ wiT, __bf16* __restrict__ whT)
{
    __shared__ float tile[32][33];
    int bid = blockIdx.x;
    const int tid = threadIdx.x;
    if (bid < 4096) {
        const size_t idx = ((size_t)bid * 256 + tid) * 4;
        float4 v = *(const float4*)(x + idx);
        bf16x4 o = { (__bf16)v.x, (__bf16)v.y, (__bf16)v.z, (__bf16)v.w };
        *(bf16x4*)(xb + idx) = o;
        return;
    }
    bid -= 4096;
    int bx = bid & 127;            // 0..127
    const int by = bid >> 7;       // 0..31
    const float* src; __bf16* dst; int sn;
    if (bx < 96) { src = w_in;  dst = wiT; sn = 3072; }
    else         { bx -= 96; src = w_out; dst = whT; sn = 1024; }
    const int tx = tid & 31, ty = tid >> 5;
    #pragma unroll
    for (int i = 0; i < 4; ++i)
        tile[ty + i * 8][tx] = src[(size_t)(by * 32 + ty + i * 8) * sn + bx * 32 + tx];
    __syncthreads();
    #pragma unroll
    for (int i = 0; i < 4; ++i) {
        float v = tile[tx][ty + i * 8];
        dst[(size_t)(bx * 32 + ty + i * 8) * 1024 + by * 32 + tx] = (__bf16)v;
    }
}

// ---------------------------------------------------------------------------
// bf16 MFMA GEMM for in-projection. 128x128 tile, BK=64. Epilogue scatters
// Q (pre-scaled by QSCALE), K, V -- ALL coalesced [bh][t][d]. grid (24, 32)
// ---------------------------------------------------------------------------
__global__ __launch_bounds__(256) void gemm_qkv_kernel(
    const __bf16* __restrict__ A, const __bf16* __restrict__ BT,
    const float* __restrict__ bias,
    __bf16* __restrict__ Oq, __bf16* __restrict__ Ok, __bf16* __restrict__ Ov)
{
    __shared__ __align__(16) __bf16 As[128 * 64];
    __shared__ __align__(16) __bf16 Bs[128 * 64];
    const int tid = threadIdx.x;
    const int wave = tid >> 6, lane = tid & 63;
    const int l16 = lane & 15, quad = lane >> 4;
    const int wm = wave >> 1, wn = wave & 1;
    const int m0 = blockIdx.y * 128, n0 = blockIdx.x * 128;

    f32x4 acc[4][4];
    #pragma unroll
    for (int mt = 0; mt < 4; ++mt)
        #pragma unroll
        for (int nt = 0; nt < 4; ++nt)
            #pragma unroll
            for (int r = 0; r < 4; ++r) acc[mt][nt][r] = 0.f;

    int smrow[4], schunk[4], sbase[4];
    #pragma unroll
    for (int i = 0; i < 4; ++i) {
        int linear = (wave * 4 + i) * 64 + lane;
        smrow[i] = linear >> 3;
        schunk[i] = (linear & 7) ^ (smrow[i] & 7);
        sbase[i] = (wave * 4 + i) * 512;
    }

    for (int k0 = 0; k0 < 1024; k0 += 64) {
        #pragma unroll
        for (int i = 0; i < 4; ++i) {
            gload_lds16(A + (size_t)(m0 + smrow[i]) * 1024 + k0 + schunk[i] * 8,
                        As + sbase[i]);
            gload_lds16(BT + (size_t)(n0 + smrow[i]) * 1024 + k0 + schunk[i] * 8,
                        Bs + sbase[i]);
        }
        __syncthreads();
        #pragma unroll
        for (int kk = 0; kk < 2; ++kk) {
            bf16x8 am[4], bn[4];
            #pragma unroll
            for (int mt = 0; mt < 4; ++mt) {
                int row = wm * 64 + mt * 16 + l16;
                int c = (kk * 4 + quad) ^ (row & 7);
                am[mt] = *(const bf16x8*)(As + row * 64 + c * 8);
            }
            #pragma unroll
            for (int nt = 0; nt < 4; ++nt) {
                int row = wn * 64 + nt * 16 + l16;
                int c = (kk * 4 + quad) ^ (row & 7);
                bn[nt] = *(const bf16x8*)(Bs + row * 64 + c * 8);
            }
            #pragma unroll
            for (int mt = 0; mt < 4; ++mt)
                #pragma unroll
                for (int nt = 0; nt < 4; ++nt)
                    acc[mt][nt] = __builtin_amdgcn_mfma_f32_16x16x32_bf16(
                        am[mt], bn[nt], acc[mt][nt], 0, 0, 0);
        }
        __syncthreads();
    }

    #pragma unroll
    for (int nt = 0; nt < 4; ++nt) {
        const int col = n0 + wn * 64 + nt * 16 + l16;
        const float bv = bias[col];
        const int sec = col >> 10, f = col & 1023;
        const int h = f >> 6, d = f & 63;
        #pragma unroll
        for (int mt = 0; mt < 4; ++mt)
            #pragma unroll
            for (int r = 0; r < 4; ++r) {
                const int row = m0 + wm * 64 + mt * 16 + quad * 4 + r;
                float v = acc[mt][nt][r] + bv;
                const int t = row >> 1, b = row & 1;
                const int bh = b * NHEAD + h;
                const size_t idx = ((size_t)bh * TSEQ + t) * HDIM + d;
                if (sec == 0)
                    Oq[idx] = (__bf16)(v * QSCALE);
                else if (sec == 1)
                    Ok[idx] = (__bf16)v;
                else
                    Ov[idx] = (__bf16)v;   // coalesced now; vtrans transposes
            }
    }
}

// ---------------------------------------------------------------------------
// V [bh][t][d] -> Vt [bh][d][t]. 64x64 LDS tile, pad-67 stride (2-way-only
// bank pattern both directions). grid (32, 32), block 256.
// ---------------------------------------------------------------------------
__global__ __launch_bounds__(256) void vtrans_kernel(
    const __bf16* __restrict__ V, __bf16* __restrict__ Vt)
{
    __shared__ __bf16 T[64 * 67];
    const int bh = blockIdx.y;
    const int t0 = blockIdx.x * 64;
    const int tid = threadIdx.x;
    const int r = tid >> 2;            // t-row 0..63
    const int c = (tid & 3) * 16;      // d-col base
    const __bf16* src = V + ((size_t)bh * TSEQ + t0 + r) * HDIM + c;
    bf16x8 a = *(const bf16x8*)src;
    bf16x8 b = *(const bf16x8*)(src + 8);
    #pragma unroll
    for (int j = 0; j < 8; ++j) {
        T[r * 67 + c + j] = a[j];
        T[r * 67 + c + 8 + j] = b[j];
    }
    __syncthreads();
    const int dr = tid >> 2;           // d-row 0..63
    const int tc = (tid & 3) * 16;     // t-col base
    bf16x8 o0, o1;
    #pragma unroll
    for (int j = 0; j < 8; ++j) {
        o0[j] = T[(tc + j) * 67 + dr];
        o1[j] = T[(tc + 8 + j) * 67 + dr];
    }
    __bf16* dst = Vt + ((size_t)bh * HDIM + dr) * TSEQ + t0 + tc;
    *(bf16x8*)dst = o0;
    *(bf16x8*)(dst + 8) = o1;
}

// ---------------------------------------------------------------------------
// MFMA flash attention v9: v8 math + restructured scheduling.
//  - 8 waves x 64 q = 512 q per block; grid 512 (2 blocks/CU exactly, no
//    tail). Each SIMD now holds 4 waves from 2 independent blocks ->
//    cross-wave MFMA/VALU/LDS overlap actually possible (v8 had 1 wave/SIMD
//    per block and duration ~= SUM of pipe times).
//  - counted-vmcnt pipeline (T4): 3 LDS buffers, 2-tile-deep prefetch,
//    raw {s_waitcnt vmcnt(2); s_barrier} -- never drains to 0 in the loop.
//    WAR-safe: buf (kt+2)%3 was last read at compute(kt-1); every wave's
//    reads are consumed before it passes barrier kt (MFMA operands force
//    lgkmcnt waits), so post-barrier staging cannot race; per-iter barrier
//    bounds inter-wave drift to 1 tile.
//  - s_setprio(1) around MFMA clusters (T5) -- pays now that waves sit at
//    diverse phases.
// LDS 48KB (2 blocks/CU = 96KB). XCD-bijective decode (512%8==0): XCD c
// owns grp = c*16 + j/4 (grp = bh*4+z), 3MB Q/K/V set per XCD L2.
// ---------------------------------------------------------------------------
__global__ __launch_bounds__(512, 4) void attn_mfma_kernel(
    const __bf16* __restrict__ Q, const __bf16* __restrict__ K,
    const __bf16* __restrict__ Vt,
    __bf16* __restrict__ O0, __bf16* __restrict__ O1,
    __bf16* __restrict__ O2, __bf16* __restrict__ O3,
    float* __restrict__ L0, float* __restrict__ L1,
    float* __restrict__ L2, float* __restrict__ L3)
{
    __shared__ __align__(16) __bf16 Ks[3][64 * 64];     // 24KB
    __shared__ __align__(16) __bf16 Vs[3][64 * 64];     // 24KB

    const int tid  = threadIdx.x;
    const int wave = tid >> 6;         // 0..7
    const int lane = tid & 63;
    const int l31  = lane & 31;
    const int hi   = lane >> 5;
    const int m7   = l31 & 7;

    // XCD-aware decode: hardware assigns XCD = blockIdx.x % 8 (round-robin).
    const int lid = blockIdx.x;        // 0..511
    const int xcd = lid & 7;
    const int j   = lid >> 3;          // 0..63 within XCD
    const int grp = xcd * 16 + (j >> 2);   // 0..127 = bh*4 + z
    const int qb  = j & 3;             // q-tile 0..3
    const int bh  = grp >> 2;          // 0..31
    const int z   = grp & 3;           // 0..3

    const int q0   = qb * 512 + wave * 64;
    const int kbase0 = z * (TSEQ / KSPLIT);

    __bf16* __restrict__ Opart = (z == 0) ? O0 : (z == 1) ? O1 : (z == 2) ? O2 : O3;
    float*  __restrict__ Lpart = (z == 0) ? L0 : (z == 1) ? L1 : (z == 2) ? L2 : L3;

    // Q fragments (B-operand): col = q = g*32 + l31, contraction d = 16c+8hi+j
    bf16x8 qf[2][4];
    #pragma unroll
    for (int g = 0; g < 2; ++g) {
        const __bf16* Qrow =
            Q + ((size_t)bh * TSEQ + q0 + g * 32 + l31) * HDIM + 8 * hi;
        #pragma unroll
        for (int c = 0; c < 4; ++c)
            qf[g][c] = *(const bf16x8*)(Qrow + 16 * c);
    }

    // O accumulators: per (g, dt), lane holds col d = 32*dt + l31,
    // rows q = g*32 + (r&3) + 8*(r>>2) + 4*hi
    f32x16 Oacc[2][2];
    #pragma unroll
    for (int g = 0; g < 2; ++g)
        #pragma unroll
        for (int dt = 0; dt < 2; ++dt)
            #pragma unroll
            for (int r = 0; r < 16; ++r) Oacc[g][dt][r] = 0.f;
    float l4[2][4] = {{0.f, 0.f, 0.f, 0.f}, {0.f, 0.f, 0.f, 0.f}};

    const __bf16* Kbase = K + ((size_t)bh * TSEQ + kbase0) * HDIM;
    const __bf16* Vbase = Vt + (size_t)bh * HDIM * TSEQ + kbase0;

    // staging: wave w covers rows 8w..8w+7 (1 K + 1 V gload per wave)
    const int srow = wave * 8 + (lane >> 3);
    const int schk = (lane & 7) ^ (srow & 7);

#define STAGE(buf, kt)                                                        \
    {                                                                         \
        gload_lds16(Kbase + (size_t)((kt) * 64 + srow) * HDIM + schk * 8,     \
                    &Ks[buf][wave * 512]);                                    \
        gload_lds16(Vbase + (size_t)srow * TSEQ + (kt) * 64 + schk * 8,       \
                    &Vs[buf][wave * 512]);                                    \
    }

// softmax one 32-key subtile for q-group g: sacc -> pa[g][2s], pa[g][2s+1]
#define SOFTMAX(sa, g, s)                                                     \
    {                                                                         \
        float p[16];                                                          \
        _Pragma("unroll")                                                     \
        for (int r = 0; r < 16; ++r) {                                        \
            p[r] = fast_exp2((sa)[r]);                                        \
            l4[g][r & 3] += p[r];                                             \
        }                                                                     \
        unsigned x[8];                                                        \
        _Pragma("unroll")                                                     \
        for (int i = 0; i < 8; ++i)                                           \
            x[i] = cvt_pk_bf16(p[2 * i], p[2 * i + 1]);                       \
        swap32(x[0], x[2]); swap32(x[1], x[3]);                               \
        swap32(x[4], x[6]); swap32(x[5], x[7]);                               \
        pa[g][2 * (s)][0] = x[0]; pa[g][2 * (s)][1] = x[1];                   \
        pa[g][2 * (s)][2] = x[2]; pa[g][2 * (s)][3] = x[3];                   \
        pa[g][2 * (s) + 1][0] = x[4]; pa[g][2 * (s) + 1][1] = x[5];           \
        pa[g][2 * (s) + 1][2] = x[6]; pa[g][2 * (s) + 1][3] = x[7];           \
    }

    STAGE(0, 0);
    STAGE(1, 1);

    int rb = 0;          // read buffer for tile kt
    int sb = 2;          // stage buffer for tile kt+2

    for (int kt = 0; kt < NT; ++kt) {
        // wait own tile-kt staging (leave kt+1's 2 loads in flight), sync
        if (kt + 1 < NT)
            asm volatile("s_waitcnt vmcnt(2)\n\ts_barrier" ::: "memory");
        else
            asm volatile("s_waitcnt vmcnt(0)\n\ts_barrier" ::: "memory");

        // stage tile kt+2 (buf sb was last read at kt-1; all waves past
        // barrier kt have consumed it)
        if (kt + 2 < NT) STAGE(sb, kt + 2);

        // --- QK^T (swapped): S^T[k][q], k-subtiles of 32, two q-groups ---
        u32x4 pa[2][4];     // PV A-fragments, k-subtiles of 16
        #pragma unroll
        for (int s = 0; s < 2; ++s) {
            f32x16 sa0, sa1;
            #pragma unroll
            for (int r = 0; r < 16; ++r) { sa0[r] = 0.f; sa1[r] = 0.f; }
            __builtin_amdgcn_s_setprio(1);
            #pragma unroll
            for (int c = 0; c < 4; ++c) {
                // A-operand: row k = 32s + l31, contraction d = 16c + 8hi + j
                bf16x8 kf = *(const bf16x8*)(
                    &Ks[rb][(32 * s + l31) * 64 + (((c << 1) | hi) ^ m7) * 8]);
                sa0 = __builtin_amdgcn_mfma_f32_32x32x16_bf16(
                    kf, qf[0][c], sa0, 0, 0, 0);
                sa1 = __builtin_amdgcn_mfma_f32_32x32x16_bf16(
                    kf, qf[1][c], sa1, 0, 0, 0);
            }
            __builtin_amdgcn_s_setprio(0);
            // lane holds S^T[k = (r&3)+8*(r>>2)+4hi + 32s][q = g*32 + l31]
            SOFTMAX(sa0, 0, s);
            SOFTMAX(sa1, 1, s);
        }

        // --- PV: O[q][d] += P[q][k] V[k][d], 4 k-subtiles x 2 d-tiles ---
        __builtin_amdgcn_s_setprio(1);
        #pragma unroll
        for (int dt = 0; dt < 2; ++dt)
            #pragma unroll
            for (int ks = 0; ks < 4; ++ks) {
                // B-operand: col d = 32dt + l31, contraction k' = 8hi + j
                bf16x8 vf = *(const bf16x8*)(
                    &Vs[rb][(dt * 32 + l31) * 64 + (((ks << 1) | hi) ^ m7) * 8]);
                Oacc[0][dt] = __builtin_amdgcn_mfma_f32_32x32x16_bf16(
                    as_bf16x8(pa[0][ks]), vf, Oacc[0][dt], 0, 0, 0);
                Oacc[1][dt] = __builtin_amdgcn_mfma_f32_32x32x16_bf16(
                    as_bf16x8(pa[1][ks]), vf, Oacc[1][dt], 0, 0, 0);
            }
        __builtin_amdgcn_s_setprio(0);

        rb = (rb == 2) ? 0 : rb + 1;
        sb = (sb == 2) ? 0 : sb + 1;
    }
#undef STAGE
#undef SOFTMAX

    // l partial: lane and lane^32 hold complementary k-halves of the same q
    #pragma unroll
    for (int g = 0; g < 2; ++g) {
        float v = (l4[g][0] + l4[g][1]) + (l4[g][2] + l4[g][3]);
        v += __shfl_xor(v, 32);
        if (hi == 0)
            Lpart[(size_t)bh * TSEQ + q0 + g * 32 + l31] = v;
    }

    // unnormalized O partial, bf16, [bh][t][d] flat
    const size_t base = ((size_t)bh * TSEQ + q0) * HDIM;
    #pragma unroll
    for (int g = 0; g < 2; ++g)
        #pragma unroll
        for (int dt = 0; dt < 2; ++dt)
            #pragma unroll
            for (int r = 0; r < 16; ++r) {
                const int q = g * 32 + (r & 3) + 8 * (r >> 2) + 4 * hi;
                Opart[base + (size_t)q * HDIM + dt * 32 + l31] =
                    (__bf16)Oacc[g][dt][r];
            }
}

// ---------------------------------------------------------------------------
// combine 4 key-split partials: Ob = sum(Oi) / sum(li), bf16 out. grid 2048
// ---------------------------------------------------------------------------
__global__ __launch_bounds__(256) void normalize_kernel(
    const __bf16* __restrict__ O0, const __bf16* __restrict__ O1,
    const __bf16* __restrict__ O2, const __bf16* __restrict__ O3,
    const float* __restrict__ L0, const float* __restrict__ L1,
    const float* __restrict__ L2, const float* __restrict__ L3,
    __bf16* __restrict__ Ob)
{
    const size_t gid = (size_t)blockIdx.x * 256 + threadIdx.x;
    const size_t idx = gid * 8;
    const size_t qi = idx >> 6;
    const float inv = 1.f / (L0[qi] + L1[qi] + L2[qi] + L3[qi]);
    bf16x8 a = *(const bf16x8*)(O0 + idx);
    bf16x8 b = *(const bf16x8*)(O1 + idx);
    bf16x8 c = *(const bf16x8*)(O2 + idx);
    bf16x8 d = *(const bf16x8*)(O3 + idx);
    bf16x8 o;
    #pragma unroll
    for (int j = 0; j < 8; ++j)
        o[j] = (__bf16)((((float)a[j] + (float)b[j]) +
                         ((float)c[j] + (float)d[j])) * inv);
    *(bf16x8*)(Ob + idx) = o;
}

// ---------------------------------------------------------------------------
// bf16 MFMA GEMM for out-projection, 128x128/BK=64 structure. Epilogue +bias,
// fp32 store. grid (8, 32) = 256 blocks.
// ---------------------------------------------------------------------------
__global__ __launch_bounds__(256) void gemm_out_kernel(
    const __bf16* __restrict__ A, const __bf16* __restrict__ BT,
    const float* __restrict__ bias, float* __restrict__ out)
{
    __shared__ __align__(16) __bf16 As[128 * 64];
    __shared__ __align__(16) __bf16 Bs[128 * 64];
    const int tid = threadIdx.x;
    const int wave = tid >> 6, lane = tid & 63;
    const int l16 = lane & 15, quad = lane >> 4;
    const int wm = wave >> 1, wn = wave & 1;
    const int m0 = blockIdx.y * 128, n0 = blockIdx.x * 128;

    f32x4 acc[4][4];
    #pragma unroll
    for (int mt = 0; mt < 4; ++mt)
        #pragma unroll
        for (int nt = 0; nt < 4; ++nt)
            #pragma unroll
            for (int r = 0; r < 4; ++r) acc[mt][nt][r] = 0.f;

    int smrow[4], schunk[4], sbase[4];
    #pragma unroll
    for (int i = 0; i < 4; ++i) {
        int linear = (wave * 4 + i) * 64 + lane;
        smrow[i] = linear >> 3;
        schunk[i] = (linear & 7) ^ (smrow[i] & 7);
        sbase[i] = (wave * 4 + i) * 512;
    }

    for (int k0 = 0; k0 < 1024; k0 += 64) {
        #pragma unroll
        for (int i = 0; i < 4; ++i) {
            gload_lds16(A + (size_t)(m0 + smrow[i]) * 1024 + k0 + schunk[i] * 8,
                        As + sbase[i]);
            gload_lds16(BT + (size_t)(n0 + smrow[i]) * 1024 + k0 + schunk[i] * 8,
                        Bs + sbase[i]);
        }
        __syncthreads();
        #pragma unroll
        for (int kk = 0; kk < 2; ++kk) {
            bf16x8 am[4], bn[4];
            #pragma unroll
            for (int mt = 0; mt < 4; ++mt) {
                int row = wm * 64 + mt * 16 + l16;
                int c = (kk * 4 + quad) ^ (row & 7);
                am[mt] = *(const bf16x8*)(As + row * 64 + c * 8);
            }
            #pragma unroll
            for (int nt = 0; nt < 4; ++nt) {
                int row = wn * 64 + nt * 16 + l16;
                int c = (kk * 4 + quad) ^ (row & 7);
                bn[nt] = *(const bf16x8*)(Bs + row * 64 + c * 8);
            }
            #pragma unroll
            for (int mt = 0; mt < 4; ++mt)
                #pragma unroll
                for (int nt = 0; nt < 4; ++nt)
                    acc[mt][nt] = __builtin_amdgcn_mfma_f32_16x16x32_bf16(
                        am[mt], bn[nt], acc[mt][nt], 0, 0, 0);
        }
        __syncthreads();
    }

    #pragma unroll
    for (int nt = 0; nt < 4; ++nt) {
        const int col = n0 + wn * 64 + nt * 16 + l16;
        const float bv = bias[col];
        #pragma unroll
        for (int mt = 0; mt < 4; ++mt)
            #pragma unroll
            for (int r = 0; r < 4; ++r) {
                const int row = m0 + wm * 64 + mt * 16 + quad * 4 + r;
                out[(size_t)row * 1024 + col] = acc[mt][nt][r] + bv;
            }
    }
}

// ---------------------------------------------------------------------------
extern "C" void kernel_launch(void* const* d_in, const int* in_sizes, int n_in,
                              void* d_out, int out_size, void* d_ws, size_t ws_size,
                              hipStream_t stream) {
    const float* x     = (const float*)d_in[0];   // (2048, 2, 1024)
    const float* w_in  = (const float*)d_in[1];   // (1024, 3072)
    const float* b_in  = (const float*)d_in[2];   // (3072,)
    const float* w_out = (const float*)d_in[3];   // (1024, 1024)
    const float* b_out = (const float*)d_in[4];   // (1024,)
    float* out = (float*)d_out;                   // (2, 2048, 1024) flat 4096x1024

    const size_t M1 = (size_t)1024 * 1024;
    __bf16* ws  = (__bf16*)d_ws;
    __bf16* xb  = ws;                 // 4M elem
    __bf16* wiT = xb  + 4 * M1;       // 3M
    __bf16* whT = wiT + 3 * M1;       // 1M
    __bf16* Qb  = whT + 1 * M1;       // 4M
    __bf16* Kb  = Qb  + 4 * M1;       // 4M
    __bf16* Vt  = Kb  + 4 * M1;       // 4M
    __bf16* O0  = Vt  + 4 * M1;       // 4M (bf16 unnormalized partial)
    __bf16* O1  = O0  + 4 * M1;       // 4M
    float*  L0  = (float*)(O1 + 4 * M1);          // 4 x 64K floats
    float*  L1  = L0 + 65536;
    float*  L2  = L1 + 65536;
    float*  L3  = L2 + 65536;
    // d_out (16MB = 8M bf16) is dead until gemm_out: park Vb then O2/O3 there.
    // Vb is consumed by vtrans BEFORE attn writes O2 over it (stream-ordered).
    __bf16* Vb  = (__bf16*)d_out;     // [bh][t][d], coalesced gemm_qkv output
    __bf16* O2  = (__bf16*)d_out;
    __bf16* O3  = O2 + 4 * M1;
    __bf16* Ob  = xb;                 // alias: xb dead after gemm_qkv

    prep_kernel<<<8192, 256, 0, stream>>>(x, w_in, w_out, xb, wiT, whT);
    gemm_qkv_kernel<<<dim3(24, 32), 256, 0, stream>>>(
        xb, wiT, b_in, Qb, Kb, Vb);
    vtrans_kernel<<<dim3(32, 32), 256, 0, stream>>>(Vb, Vt);
    attn_mfma_kernel<<<dim3(512), 512, 0, stream>>>(
        Qb, Kb, Vt, O0, O1, O2, O3, L0, L1, L2, L3);
    normalize_kernel<<<2048, 256, 0, stream>>>(
        O0, O1, O2, O3, L0, L1, L2, L3, Ob);
    gemm_out_kernel<<<dim3(8, 32), 256, 0, stream>>>(
        Ob, whT, b_out, out);
}

// Round 5
// 195.255 us; speedup vs baseline: 2.1896x; 2.1896x over previous
//
#include <hip/hip_runtime.h>
#include <stdint.h>

#define TSEQ 2048
#define NB 2
#define EMB 1024
#define NHEAD 16
#define HDIM 64
#define KSPLIT 2
#define NT (TSEQ / KSPLIT / 64)   // 16 key-tiles per block
// 0.125 (D^-0.5) * log2(e), folded into Q at the in-proj epilogue
#define QSCALE 0.18033688f

typedef __bf16 bf16x8 __attribute__((ext_vector_type(8)));
typedef __bf16 bf16x4 __attribute__((ext_vector_type(4)));
typedef float f32x4 __attribute__((ext_vector_type(4)));
typedef float f32x16 __attribute__((ext_vector_type(16)));
typedef unsigned int u32x4 __attribute__((ext_vector_type(4)));

// async 16B global->LDS. lds base must be wave-uniform; HW scatters lane*16.
__device__ __forceinline__ void gload_lds16(const void* g, void* lds) {
    __builtin_amdgcn_global_load_lds(
        (const __attribute__((address_space(1))) unsigned int*)g,
        (__attribute__((address_space(3))) unsigned int*)lds, 16, 0, 0);
}

__device__ __forceinline__ float fast_exp2(float x) {
#if __has_builtin(__builtin_amdgcn_exp2f)
    return __builtin_amdgcn_exp2f(x);   // raw v_exp_f32; inputs bounded
#else
    return exp2f(x);
#endif
}

// packed f32 pair -> bf16x2 in one u32 (lo in [15:0], hi in [31:16])
__device__ __forceinline__ unsigned cvt_pk_bf16(float lo, float hi) {
    unsigned r;
    asm("v_cvt_pk_bf16_f32 %0, %1, %2" : "=v"(r) : "v"(lo), "v"(hi));
    return r;
}

// a[32:63] <-> b[0:31]
__device__ __forceinline__ void swap32(unsigned& a, unsigned& b) {
    asm("v_permlane32_swap_b32 %0, %1" : "+v"(a), "+v"(b));
}

__device__ __forceinline__ bf16x8 as_bf16x8(u32x4 u) {
    union { u32x4 u; bf16x8 h; } c;
    c.u = u;
    return c.h;
}

// ---------------------------------------------------------------------------
// merged prep: bid<4096 -> cvt x (4096x1024 f32 -> bf16);
// else transpose+cvt weights f32 [1024][sn] -> bf16 [sn][1024].
// grid 4096 + 128*32 = 8192, block 256.
// ---------------------------------------------------------------------------
__global__ __launch_bounds__(256) void prep_kernel(
    const float* __restrict__ x, const float* __restrict__ w_in,
    const float* __restrict__ w_out,
    __bf16* __restrict__ xb, __bf16* __restrict__ wiT, __bf16* __restrict__ whT)
{
    __shared__ float tile[32][33];
    int bid = blockIdx.x;
    const int tid = threadIdx.x;
    if (bid < 4096) {
        const size_t idx = ((size_t)bid * 256 + tid) * 4;
        float4 v = *(const float4*)(x + idx);
        bf16x4 o = { (__bf16)v.x, (__bf16)v.y, (__bf16)v.z, (__bf16)v.w };
        *(bf16x4*)(xb + idx) = o;
        return;
    }
    bid -= 4096;
    int bx = bid & 127;            // 0..127
    const int by = bid >> 7;       // 0..31
    const float* src; __bf16* dst; int sn;
    if (bx < 96) { src = w_in;  dst = wiT; sn = 3072; }
    else         { bx -= 96; src = w_out; dst = whT; sn = 1024; }
    const int tx = tid & 31, ty = tid >> 5;
    #pragma unroll
    for (int i = 0; i < 4; ++i)
        tile[ty + i * 8][tx] = src[(size_t)(by * 32 + ty + i * 8) * sn + bx * 32 + tx];
    __syncthreads();
    #pragma unroll
    for (int i = 0; i < 4; ++i) {
        float v = tile[tx][ty + i * 8];
        dst[(size_t)(bx * 32 + ty + i * 8) * 1024 + by * 32 + tx] = (__bf16)v;
    }
}

// ---------------------------------------------------------------------------
// bf16 MFMA GEMM for in-projection. 128x128 tile, BK=64. Epilogue scatters
// Q (pre-scaled by QSCALE), K, V -- ALL coalesced [bh][t][d]. grid (24, 32)
// ---------------------------------------------------------------------------
__global__ __launch_bounds__(256) void gemm_qkv_kernel(
    const __bf16* __restrict__ A, const __bf16* __restrict__ BT,
    const float* __restrict__ bias,
    __bf16* __restrict__ Oq, __bf16* __restrict__ Ok, __bf16* __restrict__ Ov)
{
    __shared__ __align__(16) __bf16 As[128 * 64];
    __shared__ __align__(16) __bf16 Bs[128 * 64];
    const int tid = threadIdx.x;
    const int wave = tid >> 6, lane = tid & 63;
    const int l16 = lane & 15, quad = lane >> 4;
    const int wm = wave >> 1, wn = wave & 1;
    const int m0 = blockIdx.y * 128, n0 = blockIdx.x * 128;

    f32x4 acc[4][4];
    #pragma unroll
    for (int mt = 0; mt < 4; ++mt)
        #pragma unroll
        for (int nt = 0; nt < 4; ++nt)
            #pragma unroll
            for (int r = 0; r < 4; ++r) acc[mt][nt][r] = 0.f;

    int smrow[4], schunk[4], sbase[4];
    #pragma unroll
    for (int i = 0; i < 4; ++i) {
        int linear = (wave * 4 + i) * 64 + lane;
        smrow[i] = linear >> 3;
        schunk[i] = (linear & 7) ^ (smrow[i] & 7);
        sbase[i] = (wave * 4 + i) * 512;
    }

    for (int k0 = 0; k0 < 1024; k0 += 64) {
        #pragma unroll
        for (int i = 0; i < 4; ++i) {
            gload_lds16(A + (size_t)(m0 + smrow[i]) * 1024 + k0 + schunk[i] * 8,
                        As + sbase[i]);
            gload_lds16(BT + (size_t)(n0 + smrow[i]) * 1024 + k0 + schunk[i] * 8,
                        Bs + sbase[i]);
        }
        __syncthreads();
        #pragma unroll
        for (int kk = 0; kk < 2; ++kk) {
            bf16x8 am[4], bn[4];
            #pragma unroll
            for (int mt = 0; mt < 4; ++mt) {
                int row = wm * 64 + mt * 16 + l16;
                int c = (kk * 4 + quad) ^ (row & 7);
                am[mt] = *(const bf16x8*)(As + row * 64 + c * 8);
            }
            #pragma unroll
            for (int nt = 0; nt < 4; ++nt) {
                int row = wn * 64 + nt * 16 + l16;
                int c = (kk * 4 + quad) ^ (row & 7);
                bn[nt] = *(const bf16x8*)(Bs + row * 64 + c * 8);
            }
            #pragma unroll
            for (int mt = 0; mt < 4; ++mt)
                #pragma unroll
                for (int nt = 0; nt < 4; ++nt)
                    acc[mt][nt] = __builtin_amdgcn_mfma_f32_16x16x32_bf16(
                        am[mt], bn[nt], acc[mt][nt], 0, 0, 0);
        }
        __syncthreads();
    }

    #pragma unroll
    for (int nt = 0; nt < 4; ++nt) {
        const int col = n0 + wn * 64 + nt * 16 + l16;
        const float bv = bias[col];
        const int sec = col >> 10, f = col & 1023;
        const int h = f >> 6, d = f & 63;
        #pragma unroll
        for (int mt = 0; mt < 4; ++mt)
            #pragma unroll
            for (int r = 0; r < 4; ++r) {
                const int row = m0 + wm * 64 + mt * 16 + quad * 4 + r;
                float v = acc[mt][nt][r] + bv;
                const int t = row >> 1, b = row & 1;
                const int bh = b * NHEAD + h;
                const size_t idx = ((size_t)bh * TSEQ + t) * HDIM + d;
                if (sec == 0)
                    Oq[idx] = (__bf16)(v * QSCALE);
                else if (sec == 1)
                    Ok[idx] = (__bf16)v;
                else
                    Ov[idx] = (__bf16)v;   // coalesced now; vtrans transposes
            }
    }
}

// ---------------------------------------------------------------------------
// V [bh][t][d] -> Vt [bh][d][t]. 64x64 LDS tile, pad-67 stride (2-way-only
// bank pattern both directions). grid (32, 32), block 256.
// ---------------------------------------------------------------------------
__global__ __launch_bounds__(256) void vtrans_kernel(
    const __bf16* __restrict__ V, __bf16* __restrict__ Vt)
{
    __shared__ __bf16 T[64 * 67];
    const int bh = blockIdx.y;
    const int t0 = blockIdx.x * 64;
    const int tid = threadIdx.x;
    const int r = tid >> 2;            // t-row 0..63
    const int c = (tid & 3) * 16;      // d-col base
    const __bf16* src = V + ((size_t)bh * TSEQ + t0 + r) * HDIM + c;
    bf16x8 a = *(const bf16x8*)src;
    bf16x8 b = *(const bf16x8*)(src + 8);
    #pragma unroll
    for (int j = 0; j < 8; ++j) {
        T[r * 67 + c + j] = a[j];
        T[r * 67 + c + 8 + j] = b[j];
    }
    __syncthreads();
    const int dr = tid >> 2;           // d-row 0..63
    const int tc = (tid & 3) * 16;     // t-col base
    bf16x8 o0, o1;
    #pragma unroll
    for (int j = 0; j < 8; ++j) {
        o0[j] = T[(tc + j) * 67 + dr];
        o1[j] = T[(tc + 8 + j) * 67 + dr];
    }
    __bf16* dst = Vt + ((size_t)bh * HDIM + dr) * TSEQ + t0 + tc;
    *(bf16x8*)dst = o0;
    *(bf16x8*)(dst + 8) = o1;
}

// ---------------------------------------------------------------------------
// MFMA flash attention v10 = v8 exact structure (proven 47.5us) at KSPLIT=2.
// Swapped 32x32x16 QK^T, in-register softmax (cvt_pk + permlane32_swap),
// q-register-blocking 64q/wave (MFMA:ds_read = 2:1), Ks/Vs double-buffered,
// one barrier per tile. 4 waves x 64 q = 256 q/block. NT=16 tiles.
// Grid 512 flat, XCD-bijective (512%8==0): XCD c owns grp = c*8 + j/8
// (grp = bh*2 + z) -> 4 bh (3MB Q/K/V) per XCD L2. LDS 32KB, VGPR ~120.
// ---------------------------------------------------------------------------
__global__ __launch_bounds__(256, 2) void attn_mfma_kernel(
    const __bf16* __restrict__ Q, const __bf16* __restrict__ K,
    const __bf16* __restrict__ Vt,
    __bf16* __restrict__ O0, __bf16* __restrict__ O1,
    float* __restrict__ L0, float* __restrict__ L1)
{
    __shared__ __align__(16) __bf16 Ks[2][64 * 64];     // 16KB
    __shared__ __align__(16) __bf16 Vs[2][64 * 64];     // 16KB

    const int tid  = threadIdx.x;
    const int wave = tid >> 6;
    const int lane = tid & 63;
    const int l31  = lane & 31;
    const int hi   = lane >> 5;
    const int m7   = l31 & 7;

    // XCD-aware decode: hardware assigns XCD = blockIdx.x % 8 (round-robin).
    const int lid = blockIdx.x;        // 0..511
    const int xcd = lid & 7;
    const int j   = lid >> 3;          // 0..63 within XCD
    const int grp = xcd * 8 + (j >> 3);    // 0..63 = bh*2 + z
    const int qb  = j & 7;             // q-tile 0..7
    const int bh  = grp >> 1;          // 0..31
    const int z   = grp & 1;           // 0..1

    const int q0   = qb * 256 + wave * 64;
    const int kbase0 = z * (TSEQ / KSPLIT);

    __bf16* __restrict__ Opart = (z == 0) ? O0 : O1;
    float*  __restrict__ Lpart = (z == 0) ? L0 : L1;

    // Q fragments (B-operand): col = q = g*32 + l31, contraction d = 16c+8hi+j
    bf16x8 qf[2][4];
    #pragma unroll
    for (int g = 0; g < 2; ++g) {
        const __bf16* Qrow =
            Q + ((size_t)bh * TSEQ + q0 + g * 32 + l31) * HDIM + 8 * hi;
        #pragma unroll
        for (int c = 0; c < 4; ++c)
            qf[g][c] = *(const bf16x8*)(Qrow + 16 * c);
    }

    // O accumulators: per (g, dt), lane holds col d = 32*dt + l31,
    // rows q = g*32 + (r&3) + 8*(r>>2) + 4*hi
    f32x16 Oacc[2][2];
    #pragma unroll
    for (int g = 0; g < 2; ++g)
        #pragma unroll
        for (int dt = 0; dt < 2; ++dt)
            #pragma unroll
            for (int r = 0; r < 16; ++r) Oacc[g][dt][r] = 0.f;
    float l4[2][4] = {{0.f, 0.f, 0.f, 0.f}, {0.f, 0.f, 0.f, 0.f}};

    const __bf16* Kbase = K + ((size_t)bh * TSEQ + kbase0) * HDIM;
    const __bf16* Vbase = Vt + (size_t)bh * HDIM * TSEQ + kbase0;

    int srow[2], schk[2];
    #pragma unroll
    for (int i = 0; i < 2; ++i) {
        const int s = wave * 2 + i;
        srow[i] = s * 8 + (lane >> 3);
        schk[i] = (lane & 7) ^ (srow[i] & 7);
    }

#define STAGE(buf, kt)                                                        \
    {                                                                         \
        _Pragma("unroll")                                                     \
        for (int i = 0; i < 2; ++i) {                                         \
            const int s = wave * 2 + i;                                       \
            gload_lds16(Kbase + (size_t)((kt) * 64 + srow[i]) * HDIM          \
                            + schk[i] * 8,                                    \
                        &Ks[buf][s * 512]);                                   \
            gload_lds16(Vbase + (size_t)srow[i] * TSEQ + (kt) * 64            \
                            + schk[i] * 8,                                    \
                        &Vs[buf][s * 512]);                                   \
        }                                                                     \
    }

// softmax one 32-key subtile for q-group g: sacc -> pa[g][2s], pa[g][2s+1]
#define SOFTMAX(sa, g, s)                                                     \
    {                                                                         \
        float p[16];                                                          \
        _Pragma("unroll")                                                     \
        for (int r = 0; r < 16; ++r) {                                        \
            p[r] = fast_exp2((sa)[r]);                                        \
            l4[g][r & 3] += p[r];                                             \
        }                                                                     \
        unsigned x[8];                                                        \
        _Pragma("unroll")                                                     \
        for (int i = 0; i < 8; ++i)                                           \
            x[i] = cvt_pk_bf16(p[2 * i], p[2 * i + 1]);                       \
        swap32(x[0], x[2]); swap32(x[1], x[3]);                               \
        swap32(x[4], x[6]); swap32(x[5], x[7]);                               \
        pa[g][2 * (s)][0] = x[0]; pa[g][2 * (s)][1] = x[1];                   \
        pa[g][2 * (s)][2] = x[2]; pa[g][2 * (s)][3] = x[3];                   \
        pa[g][2 * (s) + 1][0] = x[4]; pa[g][2 * (s) + 1][1] = x[5];           \
        pa[g][2 * (s) + 1][2] = x[6]; pa[g][2 * (s) + 1][3] = x[7];           \
    }

    STAGE(0, 0);

    for (int kt = 0; kt < NT; ++kt) {
        const int b = kt & 1;
        __syncthreads();                    // staging of buf b complete
        if (kt + 1 < NT) STAGE(b ^ 1, kt + 1);  // overlap next-tile loads

        // --- QK^T (swapped): S^T[k][q], k-subtiles of 32, two q-groups ---
        u32x4 pa[2][4];     // PV A-fragments, k-subtiles of 16
        #pragma unroll
        for (int s = 0; s < 2; ++s) {
            f32x16 sa0, sa1;
            #pragma unroll
            for (int r = 0; r < 16; ++r) { sa0[r] = 0.f; sa1[r] = 0.f; }
            #pragma unroll
            for (int c = 0; c < 4; ++c) {
                // A-operand: row k = 32s + l31, contraction d = 16c + 8hi + j
                bf16x8 kf = *(const bf16x8*)(
                    &Ks[b][(32 * s + l31) * 64 + (((c << 1) | hi) ^ m7) * 8]);
                sa0 = __builtin_amdgcn_mfma_f32_32x32x16_bf16(
                    kf, qf[0][c], sa0, 0, 0, 0);
                sa1 = __builtin_amdgcn_mfma_f32_32x32x16_bf16(
                    kf, qf[1][c], sa1, 0, 0, 0);
            }
            // lane holds S^T[k = (r&3)+8*(r>>2)+4hi + 32s][q = g*32 + l31]
            SOFTMAX(sa0, 0, s);
            SOFTMAX(sa1, 1, s);
        }

        // --- PV: O[q][d] += P[q][k] V[k][d], 4 k-subtiles x 2 d-tiles ---
        #pragma unroll
        for (int dt = 0; dt < 2; ++dt)
            #pragma unroll
            for (int ks = 0; ks < 4; ++ks) {
                // B-operand: col d = 32dt + l31, contraction k' = 8hi + j
                bf16x8 vf = *(const bf16x8*)(
                    &Vs[b][(dt * 32 + l31) * 64 + (((ks << 1) | hi) ^ m7) * 8]);
                Oacc[0][dt] = __builtin_amdgcn_mfma_f32_32x32x16_bf16(
                    as_bf16x8(pa[0][ks]), vf, Oacc[0][dt], 0, 0, 0);
                Oacc[1][dt] = __builtin_amdgcn_mfma_f32_32x32x16_bf16(
                    as_bf16x8(pa[1][ks]), vf, Oacc[1][dt], 0, 0, 0);
            }
    }
#undef STAGE
#undef SOFTMAX

    // l partial: lane and lane^32 hold complementary k-halves of the same q
    #pragma unroll
    for (int g = 0; g < 2; ++g) {
        float v = (l4[g][0] + l4[g][1]) + (l4[g][2] + l4[g][3]);
        v += __shfl_xor(v, 32);
        if (hi == 0)
            Lpart[(size_t)bh * TSEQ + q0 + g * 32 + l31] = v;
    }

    // unnormalized O partial, bf16, [bh][t][d] flat
    const size_t base = ((size_t)bh * TSEQ + q0) * HDIM;
    #pragma unroll
    for (int g = 0; g < 2; ++g)
        #pragma unroll
        for (int dt = 0; dt < 2; ++dt)
            #pragma unroll
            for (int r = 0; r < 16; ++r) {
                const int q = g * 32 + (r & 3) + 8 * (r >> 2) + 4 * hi;
                Opart[base + (size_t)q * HDIM + dt * 32 + l31] =
                    (__bf16)Oacc[g][dt][r];
            }
}

// ---------------------------------------------------------------------------
// combine 2 key-split partials: Ob = (O0+O1) / (l0+l1), bf16 out. grid 2048
// ---------------------------------------------------------------------------
__global__ __launch_bounds__(256) void normalize_kernel(
    const __bf16* __restrict__ O0, const __bf16* __restrict__ O1,
    const float* __restrict__ L0, const float* __restrict__ L1,
    __bf16* __restrict__ Ob)
{
    const size_t gid = (size_t)blockIdx.x * 256 + threadIdx.x;
    const size_t idx = gid * 8;
    const size_t qi = idx >> 6;
    const float inv = 1.f / (L0[qi] + L1[qi]);
    bf16x8 a = *(const bf16x8*)(O0 + idx);
    bf16x8 b = *(const bf16x8*)(O1 + idx);
    bf16x8 o;
    #pragma unroll
    for (int j = 0; j < 8; ++j)
        o[j] = (__bf16)(((float)a[j] + (float)b[j]) * inv);
    *(bf16x8*)(Ob + idx) = o;
}

// ---------------------------------------------------------------------------
// bf16 MFMA GEMM for out-projection, 128x128/BK=64 structure. Epilogue +bias,
// fp32 store. grid (8, 32) = 256 blocks.
// ---------------------------------------------------------------------------
__global__ __launch_bounds__(256) void gemm_out_kernel(
    const __bf16* __restrict__ A, const __bf16* __restrict__ BT,
    const float* __restrict__ bias, float* __restrict__ out)
{
    __shared__ __align__(16) __bf16 As[128 * 64];
    __shared__ __align__(16) __bf16 Bs[128 * 64];
    const int tid = threadIdx.x;
    const int wave = tid >> 6, lane = tid & 63;
    const int l16 = lane & 15, quad = lane >> 4;
    const int wm = wave >> 1, wn = wave & 1;
    const int m0 = blockIdx.y * 128, n0 = blockIdx.x * 128;

    f32x4 acc[4][4];
    #pragma unroll
    for (int mt = 0; mt < 4; ++mt)
        #pragma unroll
        for (int nt = 0; nt < 4; ++nt)
            #pragma unroll
            for (int r = 0; r < 4; ++r) acc[mt][nt][r] = 0.f;

    int smrow[4], schunk[4], sbase[4];
    #pragma unroll
    for (int i = 0; i < 4; ++i) {
        int linear = (wave * 4 + i) * 64 + lane;
        smrow[i] = linear >> 3;
        schunk[i] = (linear & 7) ^ (smrow[i] & 7);
        sbase[i] = (wave * 4 + i) * 512;
    }

    for (int k0 = 0; k0 < 1024; k0 += 64) {
        #pragma unroll
        for (int i = 0; i < 4; ++i) {
            gload_lds16(A + (size_t)(m0 + smrow[i]) * 1024 + k0 + schunk[i] * 8,
                        As + sbase[i]);
            gload_lds16(BT + (size_t)(n0 + smrow[i]) * 1024 + k0 + schunk[i] * 8,
                        Bs + sbase[i]);
        }
        __syncthreads();
        #pragma unroll
        for (int kk = 0; kk < 2; ++kk) {
            bf16x8 am[4], bn[4];
            #pragma unroll
            for (int mt = 0; mt < 4; ++mt) {
                int row = wm * 64 + mt * 16 + l16;
                int c = (kk * 4 + quad) ^ (row & 7);
                am[mt] = *(const bf16x8*)(As + row * 64 + c * 8);
            }
            #pragma unroll
            for (int nt = 0; nt < 4; ++nt) {
                int row = wn * 64 + nt * 16 + l16;
                int c = (kk * 4 + quad) ^ (row & 7);
                bn[nt] = *(const bf16x8*)(Bs + row * 64 + c * 8);
            }
            #pragma unroll
            for (int mt = 0; mt < 4; ++mt)
                #pragma unroll
                for (int nt = 0; nt < 4; ++nt)
                    acc[mt][nt] = __builtin_amdgcn_mfma_f32_16x16x32_bf16(
                        am[mt], bn[nt], acc[mt][nt], 0, 0, 0);
        }
        __syncthreads();
    }

    #pragma unroll
    for (int nt = 0; nt < 4; ++nt) {
        const int col = n0 + wn * 64 + nt * 16 + l16;
        const float bv = bias[col];
        #pragma unroll
        for (int mt = 0; mt < 4; ++mt)
            #pragma unroll
            for (int r = 0; r < 4; ++r) {
                const int row = m0 + wm * 64 + mt * 16 + quad * 4 + r;
                out[(size_t)row * 1024 + col] = acc[mt][nt][r] + bv;
            }
    }
}

// ---------------------------------------------------------------------------
extern "C" void kernel_launch(void* const* d_in, const int* in_sizes, int n_in,
                              void* d_out, int out_size, void* d_ws, size_t ws_size,
                              hipStream_t stream) {
    const float* x     = (const float*)d_in[0];   // (2048, 2, 1024)
    const float* w_in  = (const float*)d_in[1];   // (1024, 3072)
    const float* b_in  = (const float*)d_in[2];   // (3072,)
    const float* w_out = (const float*)d_in[3];   // (1024, 1024)
    const float* b_out = (const float*)d_in[4];   // (1024,)
    float* out = (float*)d_out;                   // (2, 2048, 1024) flat 4096x1024

    const size_t M1 = (size_t)1024 * 1024;
    __bf16* ws  = (__bf16*)d_ws;
    __bf16* xb  = ws;                 // 4M elem
    __bf16* wiT = xb  + 4 * M1;       // 3M
    __bf16* whT = wiT + 3 * M1;       // 1M
    __bf16* Qb  = whT + 1 * M1;       // 4M
    __bf16* Kb  = Qb  + 4 * M1;       // 4M
    __bf16* Vt  = Kb  + 4 * M1;       // 4M
    __bf16* O0  = Vt  + 4 * M1;       // 4M (bf16 unnormalized partial)
    __bf16* O1  = O0  + 4 * M1;       // 4M
    float*  L0  = (float*)(O1 + 4 * M1);          // 2 x 64K floats
    float*  L1  = L0 + 65536;
    // d_out (16MB) is dead until gemm_out: park Vb there. Vb is consumed by
    // vtrans BEFORE attn runs (stream-ordered); attn no longer touches d_out.
    __bf16* Vb  = (__bf16*)d_out;     // [bh][t][d], coalesced gemm_qkv output
    __bf16* Ob  = xb;                 // alias: xb dead after gemm_qkv

    prep_kernel<<<8192, 256, 0, stream>>>(x, w_in, w_out, xb, wiT, whT);
    gemm_qkv_kernel<<<dim3(24, 32), 256, 0, stream>>>(
        xb, wiT, b_in, Qb, Kb, Vb);
    vtrans_kernel<<<dim3(32, 32), 256, 0, stream>>>(Vb, Vt);
    attn_mfma_kernel<<<dim3(512), 256, 0, stream>>>(
        Qb, Kb, Vt, O0, O1, L0, L1);
    normalize_kernel<<<2048, 256, 0, stream>>>(
        O0, O1, L0, L1, Ob);
    gemm_out_kernel<<<dim3(8, 32), 256, 0, stream>>>(
        Ob, whT, b_out, out);
}